// Round 1
// 564.242 us; speedup vs baseline: 1.1487x; 1.1487x over previous
//
#include <hip/hip_runtime.h>
#include <math.h>

#define NUM_LEVELS 16
#define T_SIZE (1u << 19)
#define T_MASK (T_SIZE - 1u)
#define PRIME1 2654435761u
#define PRIME2 805459861u

struct ResParams { float r[NUM_LEVELS]; };

typedef float f32x2 __attribute__((ext_vector_type(2)));
typedef float f32x4 __attribute__((ext_vector_type(4)));

__device__ __forceinline__ void nt_store_f2(float2 v, float2* p) {
    f32x2 x; x.x = v.x; x.y = v.y;
    __builtin_nontemporal_store(x, (f32x2*)p);
}
__device__ __forceinline__ float2 nt_load_f2(const float2* p) {
    f32x2 x = __builtin_nontemporal_load((const f32x2*)p);
    float2 r; r.x = x.x; r.y = x.y; return r;
}
__device__ __forceinline__ void nt_store_f4(f32x4 v, float* p) {
    __builtin_nontemporal_store(v, (f32x4*)p);
}

// Compute the 8 corner hash indices + fractional weights for one point/level.
struct CornerSet {
    unsigned idx[8];
    unsigned ux;       // integer x cell coord (parity decides paired loads)
    float fx, fy, fz;
};

__device__ __forceinline__ void calc_corners(
    float px, float py, float pz, float res, unsigned base, CornerSet& cs)
{
    // normalized = (p+1)/(2+1e-8); float32(2+1e-8)==2.0f so *0.5f is bit-identical
    float nx = (px + 1.0f) * 0.5f;
    float ny = (py + 1.0f) * 0.5f;
    float nz = (pz + 1.0f) * 0.5f;
    const float HI = 0.999999f;  // float32(1.0 - 1e-6)
    nx = fminf(fmaxf(nx, 0.0f), HI);
    ny = fminf(fmaxf(ny, 0.0f), HI);
    nz = fminf(fmaxf(nz, 0.0f), HI);

    float sx = nx * res, sy = ny * res, sz = nz * res;
    float flx = floorf(sx), fly = floorf(sy), flz = floorf(sz);
    cs.fx = sx - flx; cs.fy = sy - fly; cs.fz = sz - flz;

    unsigned ux = (unsigned)(int)flx;
    unsigned uy = (unsigned)(int)fly;
    unsigned uz = (unsigned)(int)flz;
    cs.ux = ux;

    unsigned hx0 = ux;            unsigned hx1 = ux + 1u;
    unsigned hy0 = uy * PRIME1;   unsigned hy1 = hy0 + PRIME1;
    unsigned hz0 = uz * PRIME2;   unsigned hz1 = hz0 + PRIME2;

    cs.idx[0] = base + ((hx0 ^ hy0 ^ hz0) & T_MASK);
    cs.idx[1] = base + ((hx0 ^ hy0 ^ hz1) & T_MASK);
    cs.idx[2] = base + ((hx0 ^ hy1 ^ hz0) & T_MASK);
    cs.idx[3] = base + ((hx0 ^ hy1 ^ hz1) & T_MASK);
    cs.idx[4] = base + ((hx1 ^ hy0 ^ hz0) & T_MASK);
    cs.idx[5] = base + ((hx1 ^ hy0 ^ hz1) & T_MASK);
    cs.idx[6] = base + ((hx1 ^ hy1 ^ hz0) & T_MASK);
    cs.idx[7] = base + ((hx1 ^ hy1 ^ hz1) & T_MASK);
}

// PRIMES[0]==1 => for even ux the x1-corner hash is h0^1: the two x-corners of
// each (y,z) pair sit in ADJACENT table slots -> one aligned 16B load covers
// both (4 requests instead of 8). Odd ux keeps 8 independent 8B gathers.
__device__ __forceinline__ void load_feats(
    const float2* __restrict__ table, const CornerSet& cs, float2 f[8])
{
    if ((cs.ux & 1u) == 0u) {
        const f32x4* t4 = reinterpret_cast<const f32x4*>(table);
#pragma unroll
        for (int j = 0; j < 4; ++j) {
            unsigned i0 = cs.idx[j];            // x0 corner; x1 corner = i0^1
            f32x4 v = t4[i0 >> 1];              // 16B-aligned pair {i0&~1, i0|1}
            float2 lo; lo.x = v.x; lo.y = v.y;  // slot (i0 & ~1)
            float2 hi; hi.x = v.z; hi.y = v.w;  // slot (i0 | 1)
            bool sw = (i0 & 1u) != 0u;
            f[j]     = sw ? hi : lo;            // corner x0 = slot i0
            f[4 + j] = sw ? lo : hi;            // corner x1 = slot i0^1
        }
    } else {
#pragma unroll
        for (int i = 0; i < 8; ++i) f[i] = table[cs.idx[i]];
    }
}

__device__ __forceinline__ float2 trilerp(const float2 f[8], float fx, float fy, float fz)
{
    float omz = 1.0f - fz, omy = 1.0f - fy, omx = 1.0f - fx;
    float c00x = f[0].x * omz + f[1].x * fz;
    float c00y = f[0].y * omz + f[1].y * fz;
    float c01x = f[2].x * omz + f[3].x * fz;
    float c01y = f[2].y * omz + f[3].y * fz;
    float c10x = f[4].x * omz + f[5].x * fz;
    float c10y = f[4].y * omz + f[5].y * fz;
    float c11x = f[6].x * omz + f[7].x * fz;
    float c11y = f[6].y * omz + f[7].y * fz;
    float c0x = c00x * omy + c01x * fy;
    float c0y = c00y * omy + c01y * fy;
    float c1x = c10x * omy + c11x * fy;
    float c1y = c10y * omy + c11y * fy;
    float2 o;
    o.x = c0x * omx + c1x * fx;
    o.y = c0y * omx + c1y * fx;
    return o;
}

// ---------------- Pass 1: level-phased gather (level = blockIdx.y) ----------------
// Dispatch is x-fastest => all CUs process one level at a time; every XCD caches the
// current 4 MB table in its own L2. Two ADJACENT points per thread so the two
// trilerp outputs merge into one 16B nt-store.
__global__ __launch_bounds__(256) void hashgrid_gather_kernel(
    const float* __restrict__ pos,      // [N,3]
    const float2* __restrict__ table,   // [L*T]
    float2* __restrict__ ws,            // [L][N]
    ResParams rp, int N)
{
    int level = blockIdx.y;
    int t = threadIdx.x;
    int n0 = blockIdx.x * 512 + 2 * t;
    int n1 = n0 + 1;
    bool v0 = n0 < N;
    bool v1 = n1 < N;
    if (!v0) return;

    float res = rp.r[level];
    unsigned base = (unsigned)level * T_SIZE;

    float px0 = pos[3 * n0 + 0], py0 = pos[3 * n0 + 1], pz0 = pos[3 * n0 + 2];
    int m1 = v1 ? n1 : n0;  // safe address for inactive second point
    float px1 = pos[3 * m1 + 0], py1 = pos[3 * m1 + 1], pz1 = pos[3 * m1 + 2];

    CornerSet c0, c1;
    calc_corners(px0, py0, pz0, res, base, c0);
    calc_corners(px1, py1, pz1, res, base, c1);

    float2 f0[8], f1[8];
    load_feats(table, c0, f0);
    load_feats(table, c1, f1);

    float2 o0 = trilerp(f0, c0.fx, c0.fy, c0.fz);
    float2 o1 = trilerp(f1, c1.fx, c1.fy, c1.fz);

    size_t w = (size_t)level * N + n0;   // n0 even -> 16B aligned
    if (v1) {
        f32x4 v; v.x = o0.x; v.y = o0.y; v.z = o1.x; v.w = o1.y;
        nt_store_f4(v, (float*)&ws[w]);
    } else {
        nt_store_f2(o0, &ws[w]);
    }
}

// ---------------- Pass 2: direct untile ws[L][N] -> out[N][32] ----------------
// One thread per (point, level-pair). Reads: per wave, each lane-group-of-8
// covers 64B contiguous per row (fully coalesced). Writes: 8 lanes fill each
// 128B output line with 16B stores (fully coalesced). No LDS, no syncthreads.
__global__ __launch_bounds__(256) void hashgrid_untile_kernel(
    const float2* __restrict__ ws,      // [L][N]
    float* __restrict__ out,            // [N][32] floats
    int N)
{
    int g = blockIdx.x * 256 + threadIdx.x;
    int p = g >> 3;                     // point
    int m = g & 7;                      // level pair (levels 2m, 2m+1)
    if (p >= N) return;
    float2 a = nt_load_f2(&ws[(size_t)(2 * m) * N + p]);
    float2 b = nt_load_f2(&ws[(size_t)(2 * m + 1) * N + p]);
    f32x4 v; v.x = a.x; v.y = a.y; v.z = b.x; v.w = b.y;
    nt_store_f4(v, &out[(size_t)p * 32 + m * 4]);
}

// ---------------- Fallback (ws too small): fused single-pass ----------------
__global__ __launch_bounds__(256) void hashgrid_fused_kernel(
    const float* __restrict__ pos,
    const float2* __restrict__ table,
    float2* __restrict__ out,
    ResParams rp, int N)
{
    int tid = blockIdx.x * blockDim.x + threadIdx.x;
    int n = tid >> 4;
    int l = tid & 15;
    if (n >= N) return;
    float px = pos[3 * n + 0], py = pos[3 * n + 1], pz = pos[3 * n + 2];
    CornerSet c;
    calc_corners(px, py, pz, rp.r[l], (unsigned)l * T_SIZE, c);
    float2 f[8];
    load_feats(table, c, f);
    out[tid] = trilerp(f, c.fx, c.fy, c.fz);
}

extern "C" void kernel_launch(void* const* d_in, const int* in_sizes, int n_in,
                              void* d_out, int out_size, void* d_ws, size_t ws_size,
                              hipStream_t stream) {
    const float*  pos   = (const float*)d_in[0];
    const float2* table = (const float2*)d_in[1];
    int N = in_sizes[0] / 3;

    ResParams rp;
    double growth = exp((log(2048.0) - log(16.0)) / 15.0);
    for (int l = 0; l < NUM_LEVELS; ++l) {
        rp.r[l] = (float)ceil(16.0 * pow(growth, (double)l));
    }

    size_t ws_needed = (size_t)NUM_LEVELS * (size_t)N * sizeof(float2);
    if (ws_size >= ws_needed) {
        float2* ws = (float2*)d_ws;
        int chunks = (N + 511) / 512;
        dim3 grid(chunks, NUM_LEVELS);
        hashgrid_gather_kernel<<<grid, 256, 0, stream>>>(pos, table, ws, rp, N);
        long long tthreads = (long long)N * 8;
        int tblocks = (int)((tthreads + 255) / 256);
        hashgrid_untile_kernel<<<tblocks, 256, 0, stream>>>(ws, (float*)d_out, N);
    } else {
        long long total = (long long)N * NUM_LEVELS;
        int grid = (int)((total + 255) / 256);
        hashgrid_fused_kernel<<<grid, 256, 0, stream>>>(pos, table, (float2*)d_out, rp, N);
    }
}